// Round 8
// baseline (391.620 us; speedup 1.0000x reference)
//
#include <hip/hip_runtime.h>

// Problem constants
#define N_NODES 25000
#define N_EDGES 200000
// MUL=16, NUM_RADIAL=8, HIDDEN=64, WNUMEL=1024
// PATH_ALPHA=1/sqrt(32), INV_SQRT3=1/sqrt(3), scales folded into B-fragments.

constexpr int NN = 32;                       // nodes per block (node kernel)
constexpr int NBLK_NODE = (N_NODES + NN - 1) / NN;   // 782

typedef __attribute__((ext_vector_type(8))) _Float16 half8;  // 8 f16 (4 VGPR)
typedef __attribute__((ext_vector_type(4))) float float4v;   // 4 fp32
typedef __attribute__((ext_vector_type(2))) float float2v;   // 2 fp32

__device__ __forceinline__ half8 h8s(half8 a, _Float16 c) { return a * c; }  // v_pk_mul_f16 x4

// ===================== CSR build chain (d_ws) =====================
__global__ __launch_bounds__(256) void csr_zero(int* __restrict__ cnt) {
    const int i = blockIdx.x * 256 + threadIdx.x;
    if (i < N_NODES) cnt[i] = 0;
}

__global__ __launch_bounds__(256) void csr_hist(const int* __restrict__ dst,
                                                int* __restrict__ cnt) {
    const int e = blockIdx.x * 256 + threadIdx.x;
    if (e < N_EDGES) atomicAdd(&cnt[dst[e]], 1);
}

// single block, 1024 threads: exclusive scan of cnt -> off, re-zero cnt (cursor)
__global__ __launch_bounds__(1024) void csr_scan(const int* __restrict__ cnt_in,
                                                 int* __restrict__ off,
                                                 int* __restrict__ cnt_clear) {
    __shared__ int ts[1024];
    const int t = threadIdx.x;
    const int base = t * 25;                  // 1024*25 = 25600 >= 25000
    int loc[25];
    int s = 0;
    #pragma unroll
    for (int i = 0; i < 25; ++i) {
        const int idx = base + i;
        const int v = (idx < N_NODES) ? cnt_in[idx] : 0;
        loc[i] = s; s += v;
    }
    ts[t] = s;
    __syncthreads();
    for (int d = 1; d < 1024; d <<= 1) {       // Hillis-Steele inclusive scan
        const int v = (t >= d) ? ts[t - d] : 0;
        __syncthreads();
        ts[t] += v;
        __syncthreads();
    }
    const int excl = ts[t] - s;
    #pragma unroll
    for (int i = 0; i < 25; ++i) {
        const int idx = base + i;
        if (idx < N_NODES) { off[idx] = excl + loc[i]; cnt_clear[idx] = 0; }
    }
    if (t == 1023) off[N_NODES] = ts[1023];    // = N_EDGES
}

__global__ __launch_bounds__(256) void csr_build(const int* __restrict__ dst,
                                                 const int* __restrict__ off,
                                                 int* __restrict__ cur,
                                                 int* __restrict__ eids) {
    const int e = blockIdx.x * 256 + threadIdx.x;
    if (e < N_EDGES) {
        const int d = dst[e];
        const int p = off[d] + atomicAdd(&cur[d], 1);
        eids[p] = e;
    }
}

// ===================== node kernel: MFMA messages + LDS segment-sum + sc =====================
// 512 threads, 8 waves. Wave w: prog = w>>1, uh = w&1. Round-7 verified MFMA core
// (lo-split dropped), combine targets an LDS accumulator (ds_add_f32), out written once.
__global__ __launch_bounds__(512, 4) void node_kernel(
    const float* __restrict__ x, const float* __restrict__ edge_attr,
    const float* __restrict__ edge_length, const int* __restrict__ edge_src,
    const int* __restrict__ edge_dst, const float* __restrict__ W1,
    const float* __restrict__ W2, const float* __restrict__ L0,
    const float* __restrict__ L1, const int* __restrict__ off,
    const int* __restrict__ eids, float* __restrict__ out) {

    const int t = threadIdx.x;
    const int w = t >> 6;             // wave id 0..7
    const int prog = w >> 1;          // which 16x16-block family of w2
    const int uh = w & 1;             // u-half
    const int qm = t & 15;            // MFMA m/n index (edge for A/C, v for B)
    const int quad = (t >> 4) & 3;    // lane quad within wave

    __shared__ __attribute__((aligned(16))) float lds_acc[NN * 64];  // node accumulator
    __shared__ __attribute__((aligned(16))) float lds_h[16 * 72];    // fp32 h, stride 72
    __shared__ __attribute__((aligned(16))) float lds_xj[16 * 68];   // gathered x[src], stride 68
    __shared__ __attribute__((aligned(16))) float lds_cf[6 * 272];   // coef planes [pl][e*17+u]
    __shared__ __attribute__((aligned(16))) float lds_xch[12 * 272]; // exchange; reused for sc x-rows
    __shared__ __attribute__((aligned(16))) float lds_w1t[64 * 8];   // W1^T [c][r]
    __shared__ __attribute__((aligned(16))) float lds_l01[512];      // L0 | L1
    __shared__ __attribute__((aligned(16))) float lds_sh[16 * 4];
    __shared__ __attribute__((aligned(16))) float lds_len[16];
    __shared__ __attribute__((aligned(16))) int   lds_dl[16];        // dst - n0

    // ---- persistent B fragments: W2 block, u-half, pre-scaled f16 ----
    // B-frag layout (16x16x32): lane holds B[k = kf*32 + quad*8 + j][n = qm]
    half8 bfr[8][2];
    {
        float scale = 0.0220970869f;                  // (1/sqrt(64)) * (1/sqrt(32))
        if (prog == 1) scale *= 0.5773502692f;        // INV_SQRT3 folded
        const int kr = quad * 8;
        #pragma unroll
        for (int up = 0; up < 8; ++up) {
            const int col = prog * 256 + (uh * 8 + up) * 16 + qm;
            #pragma unroll
            for (int kf = 0; kf < 2; ++kf) {
                half8 f;
                #pragma unroll
                for (int j = 0; j < 8; ++j) {
                    const int k = kf * 32 + kr + j;
                    f[j] = (_Float16)(W2[k * 1024 + col] * scale);
                }
                bfr[up][kf] = f;
            }
        }
    }
    {   // W1^T, L0/L1, zero accumulator
        const int r = t >> 6, c = t & 63;
        lds_w1t[c * 8 + r] = W1[t];
        lds_l01[t] = (t < 256) ? L0[t] : L1[t - 256];
        for (int i = t; i < NN * 64; i += 512) lds_acc[i] = 0.f;
    }

    const int n0 = blockIdx.x * NN;
    const int nN = min(NN, N_NODES - n0);
    const int ebeg = off[n0];
    const int eend = off[n0 + nN];
    const int ntile = (eend - ebeg + 15) >> 4;

    for (int tl = 0; tl < ntile; ++tl) {
        const int eg0 = ebeg + tl * 16;
        __syncthreads();   // orders prev-tile combine/zero before re-staging

        // ---- phase 1: meta + xj gather ----
        if (t < 16) {
            const int eg = eg0 + t;
            const int e = (eg < eend) ? eids[eg] : -1;
            if (e >= 0) {
                lds_len[t] = edge_length[e];
                const float4v ea = *(const float4v*)(edge_attr + 4 * e);
                lds_sh[t * 4 + 0] = ea[0]; lds_sh[t * 4 + 1] = ea[1];
                lds_sh[t * 4 + 2] = ea[2]; lds_sh[t * 4 + 3] = ea[3];
                lds_dl[t] = edge_dst[e] - n0;
            } else {
                lds_len[t] = 0.f;
                lds_sh[t * 4 + 0] = 0.f; lds_sh[t * 4 + 1] = 0.f;
                lds_sh[t * 4 + 2] = 0.f; lds_sh[t * 4 + 3] = 0.f;
                lds_dl[t] = 0;
            }
        }
        {
            const int e_loc = t >> 5;                 // 16 edges x 32 threads
            const int eg = eg0 + e_loc;
            const int e = (eg < eend) ? eids[eg] : -1;
            const int src = (e >= 0) ? edge_src[e] : 0;
            const int c2 = (t & 31) * 2;
            *(float2v*)(&lds_xj[e_loc * 68 + c2]) = *(const float2v*)(x + src * 64 + c2);
        }
        __syncthreads();

        if (t < 256) {
            // ---- phase 2a: coef planes (sh==0 kills invalid-edge contributions) ----
            const int e = t & 15, u = t >> 4;
            const float sh0 = lds_sh[e * 4];
            const float s1x = lds_sh[e * 4 + 1];
            const float s1y = lds_sh[e * 4 + 2];
            const float s1z = lds_sh[e * 4 + 3];
            const float xj0v = lds_xj[e * 68 + u];
            const float x0 = lds_xj[e * 68 + 16 + 3 * u];
            const float x1 = lds_xj[e * 68 + 17 + 3 * u];
            const float x2 = lds_xj[e * 68 + 18 + 3 * u];
            lds_cf[0 * 272 + e * 17 + u] = xj0v * sh0;
            lds_cf[1 * 272 + e * 17 + u] = fmaf(x0, s1x, fmaf(x1, s1y, x2 * s1z));
            lds_cf[2 * 272 + e * 17 + u] = xj0v;
            lds_cf[3 * 272 + e * 17 + u] = x0 * sh0;
            lds_cf[4 * 272 + e * 17 + u] = x1 * sh0;
            lds_cf[5 * 272 + e * 17 + u] = x2 * sh0;
            // ---- phase 2b: h = silu(radial @ W1 / sqrt(8)) -> fp32 LDS ----
            const int c0 = u * 4;
            const float len = lds_len[e];
            float rad[8];
            #pragma unroll
            for (int r = 0; r < 8; ++r) {
                const float d = len - 0.7142857143f * (float)r;
                rad[r] = __expf(-0.5f * d * d);
            }
            float4v hv;
            #pragma unroll
            for (int i = 0; i < 4; ++i) {
                const float4v wA = *(const float4v*)(&lds_w1t[(c0 + i) * 8]);
                const float4v wB = *(const float4v*)(&lds_w1t[(c0 + i) * 8 + 4]);
                float s = rad[0] * wA[0] + rad[1] * wA[1] + rad[2] * wA[2] + rad[3] * wA[3]
                        + rad[4] * wB[0] + rad[5] * wB[1] + rad[6] * wB[2] + rad[7] * wB[3];
                s *= 0.3535533906f;
                hv[i] = s / (1.f + __expf(-s));
            }
            *(float4v*)(&lds_h[e * 72 + c0]) = hv;
        }
        __syncthreads();

        // ---- phase 3: A fragments (f16 from fp32 LDS; lo-split dropped) ----
        const float* hrow = &lds_h[qm * 72];
        const float4v fa = *(const float4v*)(hrow + quad * 8);
        const float4v fb = *(const float4v*)(hrow + quad * 8 + 4);
        const float4v fc = *(const float4v*)(hrow + 32 + quad * 8);
        const float4v fd = *(const float4v*)(hrow + 32 + quad * 8 + 4);
        half8 ah0, ah1;
        #pragma unroll
        for (int j = 0; j < 4; ++j) {
            ah0[j]     = (_Float16)fa[j];
            ah0[4 + j] = (_Float16)fb[j];
            ah1[j]     = (_Float16)fc[j];
            ah1[4 + j] = (_Float16)fd[j];
        }

        // ---- MFMA with per-u coef-scaled A; C = final per-edge term ----
        if (prog < 3) {
            float4v acc = (float4v){0.f, 0.f, 0.f, 0.f};
            #pragma unroll
            for (int up = 0; up < 8; ++up) {
                const int u = uh * 8 + up;
                const _Float16 c = (_Float16)lds_cf[prog * 272 + qm * 17 + u];
                acc = __builtin_amdgcn_mfma_f32_16x16x32_f16(h8s(ah0, c), bfr[up][0], acc, 0, 0, 0);
                acc = __builtin_amdgcn_mfma_f32_16x16x32_f16(h8s(ah1, c), bfr[up][1], acc, 0, 0, 0);
            }
            float* xb = &lds_xch[w * 272];
            #pragma unroll
            for (int r = 0; r < 4; ++r) xb[(quad * 4 + r) * 17 + qm] = acc[r];
        } else {
            float4v a3[3];
            #pragma unroll
            for (int k = 0; k < 3; ++k) a3[k] = (float4v){0.f, 0.f, 0.f, 0.f};
            #pragma unroll
            for (int up = 0; up < 8; ++up) {
                const int u = uh * 8 + up;
                #pragma unroll
                for (int k = 0; k < 3; ++k) {
                    const _Float16 c = (_Float16)lds_cf[(3 + k) * 272 + qm * 17 + u];
                    a3[k] = __builtin_amdgcn_mfma_f32_16x16x32_f16(h8s(ah0, c), bfr[up][0], a3[k], 0, 0, 0);
                    a3[k] = __builtin_amdgcn_mfma_f32_16x16x32_f16(h8s(ah1, c), bfr[up][1], a3[k], 0, 0, 0);
                }
            }
            #pragma unroll
            for (int k = 0; k < 3; ++k) {
                float* xb = &lds_xch[(6 + uh * 3 + k) * 272];
                #pragma unroll
                for (int r = 0; r < 4; ++r) xb[(quad * 4 + r) * 17 + qm] = a3[k][r];
            }
        }
        __syncthreads();

        // ---- combine: 2 elems per thread, LDS float atomic into node accumulator ----
        #pragma unroll
        for (int i = 0; i < 2; ++i) {
            const int idx = t + 512 * i;          // 1024 = 16 edges x 64 elems
            const int e = idx >> 6, j = idx & 63;
            float val;
            if (j < 16) {
                val = (lds_xch[0 * 272 + e * 17 + j] + lds_xch[1 * 272 + e * 17 + j])
                    + (lds_xch[2 * 272 + e * 17 + j] + lds_xch[3 * 272 + e * 17 + j]);
            } else {
                const int q = j - 16, v = q / 3, k = q - 3 * v;
                const float s2 = lds_xch[4 * 272 + e * 17 + v] + lds_xch[5 * 272 + e * 17 + v];
                const float s3 = lds_xch[(6 + k) * 272 + e * 17 + v]
                               + lds_xch[(9 + k) * 272 + e * 17 + v];
                val = fmaf(s2, lds_sh[e * 4 + 1 + k], s3);
            }
            atomicAdd(&lds_acc[lds_dl[e] * 64 + j], val);   // ds_add_f32
        }
    }
    __syncthreads();   // all combines done

    // ---- epilogue: stage x rows (reuse xch region), out = acc + sc ----
    float* xs = lds_xch;
    for (int i = t; i < NN * 64; i += 512)
        if (i < nN * 64) xs[i] = x[n0 * 64 + i];
    __syncthreads();
    for (int i = t; i < NN * 64; i += 512) {
        if (i >= nN * 64) break;
        const int nn = i >> 6, j = i & 63;
        float s = 0.f;
        if (j < 16) {
            #pragma unroll
            for (int u = 0; u < 16; ++u) s = fmaf(xs[nn * 64 + u], lds_l01[u * 16 + j], s);
        } else {
            const int q = j - 16, v = q / 3, k = q - 3 * v;
            #pragma unroll
            for (int u = 0; u < 16; ++u)
                s = fmaf(xs[nn * 64 + 16 + 3 * u + k], lds_l01[256 + u * 16 + v], s);
        }
        out[(n0 + nn) * 64 + j] = lds_acc[i] + 0.25f * s;
    }
}

// ===================== round-7 fallback (verified) =====================
constexpr int ET = 16;
constexpr int NT = 10;
constexpr int NBLK = 1250;

__global__ __launch_bounds__(256) void sc_kernel(const float* __restrict__ x,
                                                 const float* __restrict__ L0,
                                                 const float* __restrict__ L1,
                                                 float* __restrict__ out) {
    int idx = blockIdx.x * 256 + threadIdx.x;
    if (idx >= N_NODES * 64) return;
    int n = idx >> 6, j = idx & 63;
    const float* xr = x + n * 64;
    float s = 0.f;
    if (j < 16) {
        int v = j;
        #pragma unroll
        for (int u = 0; u < 16; ++u) s = fmaf(xr[u], L0[u * 16 + v], s);
    } else {
        int v = (j - 16) / 3, k = (j - 16) % 3;
        #pragma unroll
        for (int u = 0; u < 16; ++u) s = fmaf(xr[16 + u * 3 + k], L1[u * 16 + v], s);
    }
    out[idx] = 0.25f * s;
}

__global__ __launch_bounds__(512, 4) void edge_kernel(
    const float* __restrict__ x, const float* __restrict__ edge_attr,
    const float* __restrict__ edge_length, const int* __restrict__ edge_src,
    const int* __restrict__ edge_dst, const float* __restrict__ W1,
    const float* __restrict__ W2, float* __restrict__ out) {

    const int t = threadIdx.x;
    const int w = t >> 6;
    const int prog = w >> 1;
    const int uh = w & 1;
    const int qm = t & 15;
    const int quad = (t >> 4) & 3;

    __shared__ __attribute__((aligned(16))) float lds_h[16 * 72];
    __shared__ __attribute__((aligned(16))) float lds_xj[16 * 68];
    __shared__ __attribute__((aligned(16))) float lds_cf[6 * 272];
    __shared__ __attribute__((aligned(16))) float lds_xch[12 * 272];
    __shared__ __attribute__((aligned(16))) float lds_w1t[64 * 8];
    __shared__ __attribute__((aligned(16))) float lds_sh[16 * 4];
    __shared__ __attribute__((aligned(16))) float lds_len[16];
    __shared__ __attribute__((aligned(16))) int   lds_dst[16];

    half8 bfr[8][2];
    {
        float scale = 0.0220970869f;
        if (prog == 1) scale *= 0.5773502692f;
        const int kr = quad * 8;
        #pragma unroll
        for (int up = 0; up < 8; ++up) {
            const int col = prog * 256 + (uh * 8 + up) * 16 + qm;
            #pragma unroll
            for (int kf = 0; kf < 2; ++kf) {
                half8 f;
                #pragma unroll
                for (int j = 0; j < 8; ++j) {
                    const int k = kf * 32 + kr + j;
                    f[j] = (_Float16)(W2[k * 1024 + col] * scale);
                }
                bfr[up][kf] = f;
            }
        }
    }
    {
        const int r = t >> 6, c = t & 63;
        lds_w1t[c * 8 + r] = W1[t];
    }

    for (int tl = 0; tl < NT; ++tl) {
        const int e0 = (blockIdx.x * NT + tl) * ET;
        __syncthreads();
        if (t < 16) {
            lds_dst[t] = edge_dst[e0 + t];
            lds_len[t] = edge_length[e0 + t];
            const float4v ea = *(const float4v*)(edge_attr + 4 * (e0 + t));
            lds_sh[t * 4 + 0] = ea[0]; lds_sh[t * 4 + 1] = ea[1];
            lds_sh[t * 4 + 2] = ea[2]; lds_sh[t * 4 + 3] = ea[3];
        }
        {
            const int l = t & 63;
            const int e_loc = w * 2 + (l >> 5);
            const int src = edge_src[e0 + e_loc];
            const int c2 = (l & 31) * 2;
            *(float2v*)(&lds_xj[e_loc * 68 + c2]) = *(const float2v*)(x + src * 64 + c2);
        }
        __syncthreads();
        if (t < 256) {
            const int e = t & 15, u = t >> 4;
            const float sh0 = lds_sh[e * 4];
            const float s1x = lds_sh[e * 4 + 1];
            const float s1y = lds_sh[e * 4 + 2];
            const float s1z = lds_sh[e * 4 + 3];
            const float xj0v = lds_xj[e * 68 + u];
            const float x0 = lds_xj[e * 68 + 16 + 3 * u];
            const float x1 = lds_xj[e * 68 + 17 + 3 * u];
            const float x2 = lds_xj[e * 68 + 18 + 3 * u];
            lds_cf[0 * 272 + e * 17 + u] = xj0v * sh0;
            lds_cf[1 * 272 + e * 17 + u] = fmaf(x0, s1x, fmaf(x1, s1y, x2 * s1z));
            lds_cf[2 * 272 + e * 17 + u] = xj0v;
            lds_cf[3 * 272 + e * 17 + u] = x0 * sh0;
            lds_cf[4 * 272 + e * 17 + u] = x1 * sh0;
            lds_cf[5 * 272 + e * 17 + u] = x2 * sh0;
            const int c0 = u * 4;
            const float len = lds_len[e];
            float rad[8];
            #pragma unroll
            for (int r = 0; r < 8; ++r) {
                const float d = len - 0.7142857143f * (float)r;
                rad[r] = __expf(-0.5f * d * d);
            }
            float4v hv;
            #pragma unroll
            for (int i = 0; i < 4; ++i) {
                const float4v wA = *(const float4v*)(&lds_w1t[(c0 + i) * 8]);
                const float4v wB = *(const float4v*)(&lds_w1t[(c0 + i) * 8 + 4]);
                float s = rad[0] * wA[0] + rad[1] * wA[1] + rad[2] * wA[2] + rad[3] * wA[3]
                        + rad[4] * wB[0] + rad[5] * wB[1] + rad[6] * wB[2] + rad[7] * wB[3];
                s *= 0.3535533906f;
                hv[i] = s / (1.f + __expf(-s));
            }
            *(float4v*)(&lds_h[e * 72 + c0]) = hv;
        }
        __syncthreads();
        const float* hrow = &lds_h[qm * 72];
        const float4v fa = *(const float4v*)(hrow + quad * 8);
        const float4v fb = *(const float4v*)(hrow + quad * 8 + 4);
        const float4v fc = *(const float4v*)(hrow + 32 + quad * 8);
        const float4v fd = *(const float4v*)(hrow + 32 + quad * 8 + 4);
        half8 ah0, al0, ah1, al1;
        #pragma unroll
        for (int j = 0; j < 4; ++j) {
            _Float16 hh;
            hh = (_Float16)fa[j]; ah0[j]     = hh; al0[j]     = (_Float16)(fa[j] - (float)hh);
            hh = (_Float16)fb[j]; ah0[4 + j] = hh; al0[4 + j] = (_Float16)(fb[j] - (float)hh);
            hh = (_Float16)fc[j]; ah1[j]     = hh; al1[j]     = (_Float16)(fc[j] - (float)hh);
            hh = (_Float16)fd[j]; ah1[4 + j] = hh; al1[4 + j] = (_Float16)(fd[j] - (float)hh);
        }
        if (prog < 3) {
            float4v acc = (float4v){0.f, 0.f, 0.f, 0.f};
            #pragma unroll
            for (int up = 0; up < 8; ++up) {
                const int u = uh * 8 + up;
                const _Float16 c = (_Float16)lds_cf[prog * 272 + qm * 17 + u];
                acc = __builtin_amdgcn_mfma_f32_16x16x32_f16(h8s(ah0, c), bfr[up][0], acc, 0, 0, 0);
                acc = __builtin_amdgcn_mfma_f32_16x16x32_f16(h8s(al0, c), bfr[up][0], acc, 0, 0, 0);
                acc = __builtin_amdgcn_mfma_f32_16x16x32_f16(h8s(ah1, c), bfr[up][1], acc, 0, 0, 0);
                acc = __builtin_amdgcn_mfma_f32_16x16x32_f16(h8s(al1, c), bfr[up][1], acc, 0, 0, 0);
            }
            float* xb = &lds_xch[w * 272];
            #pragma unroll
            for (int r = 0; r < 4; ++r) xb[(quad * 4 + r) * 17 + qm] = acc[r];
        } else {
            float4v a3[3];
            #pragma unroll
            for (int k = 0; k < 3; ++k) a3[k] = (float4v){0.f, 0.f, 0.f, 0.f};
            #pragma unroll
            for (int up = 0; up < 8; ++up) {
                const int u = uh * 8 + up;
                #pragma unroll
                for (int k = 0; k < 3; ++k) {
                    const _Float16 c = (_Float16)lds_cf[(3 + k) * 272 + qm * 17 + u];
                    a3[k] = __builtin_amdgcn_mfma_f32_16x16x32_f16(h8s(ah0, c), bfr[up][0], a3[k], 0, 0, 0);
                    a3[k] = __builtin_amdgcn_mfma_f32_16x16x32_f16(h8s(al0, c), bfr[up][0], a3[k], 0, 0, 0);
                    a3[k] = __builtin_amdgcn_mfma_f32_16x16x32_f16(h8s(ah1, c), bfr[up][1], a3[k], 0, 0, 0);
                    a3[k] = __builtin_amdgcn_mfma_f32_16x16x32_f16(h8s(al1, c), bfr[up][1], a3[k], 0, 0, 0);
                }
            }
            #pragma unroll
            for (int k = 0; k < 3; ++k) {
                float* xb = &lds_xch[(6 + uh * 3 + k) * 272];
                #pragma unroll
                for (int r = 0; r < 4; ++r) xb[(quad * 4 + r) * 17 + qm] = a3[k][r];
            }
        }
        __syncthreads();
        #pragma unroll
        for (int i = 0; i < 2; ++i) {
            const int idx = t + 512 * i;
            const int e = idx >> 6, j = idx & 63;
            float val;
            if (j < 16) {
                val = (lds_xch[0 * 272 + e * 17 + j] + lds_xch[1 * 272 + e * 17 + j])
                    + (lds_xch[2 * 272 + e * 17 + j] + lds_xch[3 * 272 + e * 17 + j]);
            } else {
                const int q = j - 16, v = q / 3, k = q - 3 * v;
                const float s2 = lds_xch[4 * 272 + e * 17 + v] + lds_xch[5 * 272 + e * 17 + v];
                const float s3 = lds_xch[(6 + k) * 272 + e * 17 + v]
                               + lds_xch[(9 + k) * 272 + e * 17 + v];
                val = fmaf(s2, lds_sh[e * 4 + 1 + k], s3);
            }
            atomicAdd(out + lds_dst[e] * 64 + j, val);
        }
    }
}

// ===================== host =====================
extern "C" void kernel_launch(void* const* d_in, const int* in_sizes, int n_in,
                              void* d_out, int out_size, void* d_ws, size_t ws_size,
                              hipStream_t stream) {
    const float* x           = (const float*)d_in[0];
    const float* edge_attr   = (const float*)d_in[1];
    const float* edge_length = (const float*)d_in[2];
    const int*   edge_src    = (const int*)d_in[3];
    const int*   edge_dst    = (const int*)d_in[4];
    const float* W1          = (const float*)d_in[5];
    const float* W2          = (const float*)d_in[6];
    const float* L0          = (const float*)d_in[7];
    const float* L1          = (const float*)d_in[8];
    float* out = (float*)d_out;

    const size_t need = (size_t)(25008 + 25008 + N_EDGES) * 4;
    if (ws_size >= need) {
        int* off = (int*)d_ws;            // 25001 used, 25008 reserved
        int* cnt = off + 25008;           // 25000
        int* eid = cnt + 25008;           // 200000
        csr_zero<<<(N_NODES + 255) / 256, 256, 0, stream>>>(cnt);
        csr_hist<<<(N_EDGES + 255) / 256, 256, 0, stream>>>(edge_dst, cnt);
        csr_scan<<<1, 1024, 0, stream>>>(cnt, off, cnt);
        csr_build<<<(N_EDGES + 255) / 256, 256, 0, stream>>>(edge_dst, off, cnt, eid);
        node_kernel<<<NBLK_NODE, 512, 0, stream>>>(
            x, edge_attr, edge_length, edge_src, edge_dst, W1, W2, L0, L1, off, eid, out);
    } else {
        sc_kernel<<<(N_NODES * 64 + 255) / 256, 256, 0, stream>>>(x, L0, L1, out);
        edge_kernel<<<NBLK, 512, 0, stream>>>(
            x, edge_attr, edge_length, edge_src, edge_dst, W1, W2, out);
    }
}

// Round 9
// 261.077 us; speedup vs baseline: 1.5000x; 1.5000x over previous
//
#include <hip/hip_runtime.h>

// Problem constants
#define N_NODES 25000
#define N_EDGES 200000
// MUL=16, NUM_RADIAL=8, HIDDEN=64, WNUMEL=1024
// PATH_ALPHA=1/sqrt(32), INV_SQRT3=1/sqrt(3), scales folded into B-fragments.

constexpr int ET = 32;      // edges per tile (round 9: was 16)
constexpr int NT = 5;       // tiles per block
constexpr int NBLK = 1250;  // 1250*5*32 = 200000 edges exactly

typedef __attribute__((ext_vector_type(8))) _Float16 half8;  // 8 f16 (4 VGPR)
typedef __attribute__((ext_vector_type(4))) float float4v;   // 4 fp32

__device__ __forceinline__ half8 h8s(half8 a, _Float16 c) { return a * c; }  // v_pk_mul_f16 x4

// ---------------- self-connection (round-7 verified version) ----------------
__global__ __launch_bounds__(256) void sc_kernel(const float* __restrict__ x,
                                                 const float* __restrict__ L0,
                                                 const float* __restrict__ L1,
                                                 float* __restrict__ out) {
    __shared__ float l0[256], l1[256];
    __shared__ float xs[4][68];
    const int t = threadIdx.x;
    l0[t] = L0[t];
    l1[t] = L1[t];
    const int g = t >> 6, j = t & 63;
    const int n = blockIdx.x * 4 + g;          // 6250 blocks x 4 nodes
    xs[g][j] = x[n * 64 + j];                  // coalesced
    __syncthreads();
    float s = 0.f;
    if (j < 16) {
        #pragma unroll
        for (int u = 0; u < 16; ++u) s = fmaf(xs[g][u], l0[u * 16 + j], s);
    } else {
        const int q = j - 16, v = q / 3, k = q - 3 * v;
        #pragma unroll
        for (int u = 0; u < 16; ++u) s = fmaf(xs[g][16 + 3 * u + k], l1[u * 16 + v], s);
    }
    out[n * 64 + j] = 0.25f * s;   // 1/sqrt(MUL)
}

// ---------------- edge kernel: 32-edge tiles, 2 MFMA m-tiles, no lo-split ----------------
// 512 threads, 8 waves. Wave w: prog = w>>1, uh = w&1 (u in [uh*8, uh*8+8)).
// Per u, A fragment (h rows mt*16+qm, f16) scaled by coef[e][u] feeds MFMA:
//   C[e][v] = sum_u coef[e][u] * sum_c h[e][c]*W2[c][u*16+v]*scale
// Coef planes: 0: xj0*sh0 | 1: b1 | 2: xj0 | 3+k: xj1[.,k]*sh0
__global__ __launch_bounds__(512, 4) void edge_kernel(
    const float* __restrict__ x, const float* __restrict__ edge_attr,
    const float* __restrict__ edge_length, const int* __restrict__ edge_src,
    const int* __restrict__ edge_dst, const float* __restrict__ W1,
    const float* __restrict__ W2, float* __restrict__ out) {

    const int t = threadIdx.x;
    const int w = t >> 6;             // wave id 0..7
    const int prog = w >> 1;          // which 16x16-block family of w2
    const int uh = w & 1;             // u-half
    const int qm = t & 15;            // MFMA m/n index
    const int quad = (t >> 4) & 3;    // lane quad within wave

    __shared__ __attribute__((aligned(16))) float lds_h[ET * 72];    // fp32 h, stride 72
    __shared__ __attribute__((aligned(16))) float lds_xj[ET * 68];   // gathered x[src], stride 68
    __shared__ __attribute__((aligned(16))) float lds_cf[6 * ET * 17];  // coef planes [pl][e*17+u]
    __shared__ __attribute__((aligned(16))) float lds_xch[12 * ET * 17];// term exchange [pl][e*17+v]
    __shared__ __attribute__((aligned(16))) float lds_w1t[64 * 8];   // W1^T [c][r]
    __shared__ __attribute__((aligned(16))) float lds_sh[ET * 4];
    __shared__ __attribute__((aligned(16))) float lds_len[ET];
    __shared__ __attribute__((aligned(16))) int   lds_dst[ET];

    constexpr int PL = ET * 17;       // plane stride (544)

    // ---- persistent B fragments: W2 block `prog`, u-half `uh`, pre-scaled f16 ----
    // B-frag layout (16x16x32): lane holds B[k = kf*32 + quad*8 + j][n = qm]
    half8 bfr[8][2];
    {
        float scale = 0.0220970869f;                  // (1/sqrt(64)) * (1/sqrt(32))
        if (prog == 1) scale *= 0.5773502692f;        // INV_SQRT3 folded
        const int kr = quad * 8;
        #pragma unroll
        for (int up = 0; up < 8; ++up) {
            const int col = prog * 256 + (uh * 8 + up) * 16 + qm;
            #pragma unroll
            for (int kf = 0; kf < 2; ++kf) {
                half8 f;
                #pragma unroll
                for (int j = 0; j < 8; ++j) {
                    const int k = kf * 32 + kr + j;
                    f[j] = (_Float16)(W2[k * 1024 + col] * scale);
                }
                bfr[up][kf] = f;
            }
        }
    }
    // W1 -> LDS transposed [c][r]
    {
        const int r = t >> 6, c = t & 63;
        lds_w1t[c * 8 + r] = W1[t];
    }

    for (int tl = 0; tl < NT; ++tl) {
        const int e0 = (blockIdx.x * NT + tl) * ET;
        __syncthreads();   // orders prev-tile combine reads before re-staging

        // ---- phase 1: meta + xj gather (all 512 threads, float4 per thread) ----
        if (t < ET) {
            lds_dst[t] = edge_dst[e0 + t];
            lds_len[t] = edge_length[e0 + t];
            const float4v ea = *(const float4v*)(edge_attr + 4 * (e0 + t));
            lds_sh[t * 4 + 0] = ea[0]; lds_sh[t * 4 + 1] = ea[1];
            lds_sh[t * 4 + 2] = ea[2]; lds_sh[t * 4 + 3] = ea[3];
        }
        {
            const int e_loc = t >> 4;                 // 32 edges x 16 threads
            const int src = edge_src[e0 + e_loc];     // 16-thread-uniform
            const int c4 = (t & 15) * 4;
            *(float4v*)(&lds_xj[e_loc * 68 + c4]) = *(const float4v*)(x + src * 64 + c4);
        }
        __syncthreads();

        // ---- phase 2: coef planes + h (all 512 threads: e = t&31, u = t>>5) ----
        {
            const int e = t & 31, u = t >> 5;
            const float sh0 = lds_sh[e * 4];
            const float s1x = lds_sh[e * 4 + 1];
            const float s1y = lds_sh[e * 4 + 2];
            const float s1z = lds_sh[e * 4 + 3];
            const float xj0v = lds_xj[e * 68 + u];
            const float x0 = lds_xj[e * 68 + 16 + 3 * u];
            const float x1 = lds_xj[e * 68 + 17 + 3 * u];
            const float x2 = lds_xj[e * 68 + 18 + 3 * u];
            lds_cf[0 * PL + e * 17 + u] = xj0v * sh0;
            lds_cf[1 * PL + e * 17 + u] = fmaf(x0, s1x, fmaf(x1, s1y, x2 * s1z));
            lds_cf[2 * PL + e * 17 + u] = xj0v;
            lds_cf[3 * PL + e * 17 + u] = x0 * sh0;
            lds_cf[4 * PL + e * 17 + u] = x1 * sh0;
            lds_cf[5 * PL + e * 17 + u] = x2 * sh0;
            // h = silu(radial @ W1 / sqrt(8)) for (e, c0..c0+3)
            const int c0 = u * 4;
            const float len = lds_len[e];
            float rad[8];
            #pragma unroll
            for (int r = 0; r < 8; ++r) {
                const float d = len - 0.7142857143f * (float)r;
                rad[r] = __expf(-0.5f * d * d);
            }
            float4v hv;
            #pragma unroll
            for (int i = 0; i < 4; ++i) {
                const float4v wA = *(const float4v*)(&lds_w1t[(c0 + i) * 8]);
                const float4v wB = *(const float4v*)(&lds_w1t[(c0 + i) * 8 + 4]);
                float s = rad[0] * wA[0] + rad[1] * wA[1] + rad[2] * wA[2] + rad[3] * wA[3]
                        + rad[4] * wB[0] + rad[5] * wB[1] + rad[6] * wB[2] + rad[7] * wB[3];
                s *= 0.3535533906f;
                hv[i] = s / (1.f + __expf(-s));
            }
            *(float4v*)(&lds_h[e * 72 + c0]) = hv;
        }
        __syncthreads();

        // ---- phase 3: A fragments for both m-tiles (f16, no lo-split) ----
        half8 ah0[2], ah1[2];
        #pragma unroll
        for (int mt = 0; mt < 2; ++mt) {
            const float* hrow = &lds_h[(mt * 16 + qm) * 72];
            const float4v fa = *(const float4v*)(hrow + quad * 8);
            const float4v fb = *(const float4v*)(hrow + quad * 8 + 4);
            const float4v fc = *(const float4v*)(hrow + 32 + quad * 8);
            const float4v fd = *(const float4v*)(hrow + 32 + quad * 8 + 4);
            #pragma unroll
            for (int j = 0; j < 4; ++j) {
                ah0[mt][j]     = (_Float16)fa[j];
                ah0[mt][4 + j] = (_Float16)fb[j];
                ah1[mt][j]     = (_Float16)fc[j];
                ah1[mt][4 + j] = (_Float16)fd[j];
            }
        }

        // ---- MFMA with per-u coef-scaled A; C = final per-edge term ----
        // C layout per m-tile: row e = mt*16 + quad*4 + r, col v = qm
        if (prog < 3) {
            float4v acc[2];
            acc[0] = (float4v){0.f, 0.f, 0.f, 0.f};
            acc[1] = (float4v){0.f, 0.f, 0.f, 0.f};
            #pragma unroll
            for (int up = 0; up < 8; ++up) {
                const int u = uh * 8 + up;
                #pragma unroll
                for (int mt = 0; mt < 2; ++mt) {
                    const _Float16 c = (_Float16)lds_cf[prog * PL + (mt * 16 + qm) * 17 + u];
                    acc[mt] = __builtin_amdgcn_mfma_f32_16x16x32_f16(h8s(ah0[mt], c), bfr[up][0], acc[mt], 0, 0, 0);
                    acc[mt] = __builtin_amdgcn_mfma_f32_16x16x32_f16(h8s(ah1[mt], c), bfr[up][1], acc[mt], 0, 0, 0);
                }
            }
            float* xb = &lds_xch[w * PL];
            #pragma unroll
            for (int mt = 0; mt < 2; ++mt)
                #pragma unroll
                for (int r = 0; r < 4; ++r)
                    xb[(mt * 16 + quad * 4 + r) * 17 + qm] = acc[mt][r];
        } else {
            float4v a3[2][3];
            #pragma unroll
            for (int mt = 0; mt < 2; ++mt)
                #pragma unroll
                for (int k = 0; k < 3; ++k) a3[mt][k] = (float4v){0.f, 0.f, 0.f, 0.f};
            #pragma unroll
            for (int up = 0; up < 8; ++up) {
                const int u = uh * 8 + up;
                #pragma unroll
                for (int mt = 0; mt < 2; ++mt) {
                    #pragma unroll
                    for (int k = 0; k < 3; ++k) {
                        const _Float16 c = (_Float16)lds_cf[(3 + k) * PL + (mt * 16 + qm) * 17 + u];
                        a3[mt][k] = __builtin_amdgcn_mfma_f32_16x16x32_f16(h8s(ah0[mt], c), bfr[up][0], a3[mt][k], 0, 0, 0);
                        a3[mt][k] = __builtin_amdgcn_mfma_f32_16x16x32_f16(h8s(ah1[mt], c), bfr[up][1], a3[mt][k], 0, 0, 0);
                    }
                }
            }
            #pragma unroll
            for (int k = 0; k < 3; ++k) {
                float* xb = &lds_xch[(6 + uh * 3 + k) * PL];
                #pragma unroll
                for (int mt = 0; mt < 2; ++mt)
                    #pragma unroll
                    for (int r = 0; r < 4; ++r)
                        xb[(mt * 16 + quad * 4 + r) * 17 + qm] = a3[mt][k][r];
            }
        }
        __syncthreads();

        // ---- combine: 4 output elems per thread, ONE atomic each ----
        #pragma unroll
        for (int i = 0; i < 4; ++i) {
            const int idx = t + 512 * i;          // 2048 = 32 edges x 64 elems
            const int e = idx >> 6, j = idx & 63;
            float val;
            if (j < 16) {
                // m0[v=j]: p0 (sh0 in coef) + p1 (INV_SQRT3 in bfr), both uh halves
                val = (lds_xch[0 * PL + e * 17 + j] + lds_xch[1 * PL + e * 17 + j])
                    + (lds_xch[2 * PL + e * 17 + j] + lds_xch[3 * PL + e * 17 + j]);
            } else {
                const int q = j - 16, v = q / 3, k = q - 3 * v;
                // m1[v][k] = sh1[k]*p2[v] + p3k[v]  (sh0 folded into p3 coef)
                const float s2 = lds_xch[4 * PL + e * 17 + v] + lds_xch[5 * PL + e * 17 + v];
                const float s3 = lds_xch[(6 + k) * PL + e * 17 + v]
                               + lds_xch[(9 + k) * PL + e * 17 + v];
                val = fmaf(s2, lds_sh[e * 4 + 1 + k], s3);
            }
            atomicAdd(out + lds_dst[e] * 64 + j, val);
        }
        // next-iteration top barrier orders these LDS reads before re-staging
    }
}

extern "C" void kernel_launch(void* const* d_in, const int* in_sizes, int n_in,
                              void* d_out, int out_size, void* d_ws, size_t ws_size,
                              hipStream_t stream) {
    const float* x           = (const float*)d_in[0];
    const float* edge_attr   = (const float*)d_in[1];
    const float* edge_length = (const float*)d_in[2];
    const int*   edge_src    = (const int*)d_in[3];
    const int*   edge_dst    = (const int*)d_in[4];
    const float* W1          = (const float*)d_in[5];
    const float* W2          = (const float*)d_in[6];
    const float* L0          = (const float*)d_in[7];
    const float* L1          = (const float*)d_in[8];
    float* out = (float*)d_out;

    sc_kernel<<<N_NODES / 4, 256, 0, stream>>>(x, L0, L1, out);
    edge_kernel<<<NBLK, 512, 0, stream>>>(
        x, edge_attr, edge_length, edge_src, edge_dst, W1, W2, out);
}